// Round 1
// baseline (4237.225 us; speedup 1.0000x reference)
//
#include <hip/hip_runtime.h>

#define N_NODES 100000
#define N_EDGES 1600000
#define K_DIM   128   // both layers contract over 128

// ---------------- degree / normalization ----------------

__global__ __launch_bounds__(256) void k_init_deg(float* deg, int n) {
    int i = blockIdx.x * 256 + threadIdx.x;
    if (i < n) deg[i] = 1.0f;   // self-loop
}

__global__ __launch_bounds__(256) void k_count_deg(const int* __restrict__ col,
                                                   float* deg, int e) {
    int i = blockIdx.x * 256 + threadIdx.x;
    if (i < e) unsafeAtomicAdd(&deg[col[i]], 1.0f);
}

__global__ __launch_bounds__(256) void k_dinv(float* deg, int n) {
    int i = blockIdx.x * 256 + threadIdx.x;
    if (i < n) deg[i] = rsqrtf(deg[i]);   // deg >= 1 always
}

// ---------------- dense transform (fp32 VALU GEMM, W in LDS) ----------------
// A:[nrows,128] @ B:[128,F] -> H:[nrows,F]; also writes AGG = H*dinv^2 (+b_out)
// which is the self-loop init for the scatter stage.
// Thread layout: TX = F/C threads across columns (interleaved float4 slots:
// slot = s*TX + tx -> adjacent lanes read adjacent LDS float4s, 0 conflicts),
// TY = 256/TX row groups, R rows per thread. All acc indices compile-time.
template<int F, int C, int R, bool RELU_IN, bool OUT_BIAS>
__global__ __launch_bounds__(256) void k_gemm(
    const float* __restrict__ A, const float* __restrict__ B,
    const float* __restrict__ b_in, const float* __restrict__ b_out,
    const float* __restrict__ dinv,
    float* __restrict__ H, float* __restrict__ AGG, int nrows)
{
    constexpr int K  = K_DIM;
    constexpr int TX = F / C;
    constexpr int TY = 256 / TX;
    constexpr int ROWS = TY * R;
    constexpr int SL = C / 4;          // float4 slots per thread
    static_assert(TX * C == F && TX * TY == 256, "layout");

    __shared__ float Blds[K * F];
    for (int i = threadIdx.x; i < K * F / 4; i += 256)
        reinterpret_cast<float4*>(Blds)[i] = reinterpret_cast<const float4*>(B)[i];
    __syncthreads();

    const int tx = threadIdx.x % TX;
    const int ty = threadIdx.x / TX;
    const int row0 = blockIdx.x * ROWS + ty * R;

    float acc[R][C];
#pragma unroll
    for (int r = 0; r < R; ++r)
#pragma unroll
        for (int j = 0; j < C; ++j) acc[r][j] = 0.0f;

    for (int k4 = 0; k4 < K / 4; ++k4) {
        float4 a4[R];
        float4 bin;
        if constexpr (RELU_IN) bin = reinterpret_cast<const float4*>(b_in)[k4];
#pragma unroll
        for (int r = 0; r < R; ++r) {
            int row = row0 + r;
            if (row < nrows) {
                float4 v = reinterpret_cast<const float4*>(A + (size_t)row * K)[k4];
                if constexpr (RELU_IN) {
                    v.x = fmaxf(v.x + bin.x, 0.0f);
                    v.y = fmaxf(v.y + bin.y, 0.0f);
                    v.z = fmaxf(v.z + bin.z, 0.0f);
                    v.w = fmaxf(v.w + bin.w, 0.0f);
                }
                a4[r] = v;
            } else {
                a4[r] = make_float4(0.f, 0.f, 0.f, 0.f);
            }
        }
#pragma unroll
        for (int kk = 0; kk < 4; ++kk) {
            const int k = k4 * 4 + kk;
            const float4* Brow = reinterpret_cast<const float4*>(Blds + k * F);
#pragma unroll
            for (int s = 0; s < SL; ++s) {
                float4 b = Brow[s * TX + tx];
#pragma unroll
                for (int r = 0; r < R; ++r) {
                    float a = (kk == 0) ? a4[r].x : (kk == 1) ? a4[r].y
                            : (kk == 2) ? a4[r].z : a4[r].w;
                    acc[r][s*4+0] = fmaf(a, b.x, acc[r][s*4+0]);
                    acc[r][s*4+1] = fmaf(a, b.y, acc[r][s*4+1]);
                    acc[r][s*4+2] = fmaf(a, b.z, acc[r][s*4+2]);
                    acc[r][s*4+3] = fmaf(a, b.w, acc[r][s*4+3]);
                }
            }
        }
    }

#pragma unroll
    for (int r = 0; r < R; ++r) {
        int row = row0 + r;
        if (row >= nrows) continue;
        float di = dinv[row];
        float dd = di * di;
#pragma unroll
        for (int s = 0; s < SL; ++s) {
            int slot = s * TX + tx;            // float4 column slot
            float4 v = make_float4(acc[r][s*4+0], acc[r][s*4+1],
                                   acc[r][s*4+2], acc[r][s*4+3]);
            reinterpret_cast<float4*>(H + (size_t)row * F)[slot] = v;
            float4 o;
            o.x = v.x * dd; o.y = v.y * dd; o.z = v.z * dd; o.w = v.w * dd;
            if constexpr (OUT_BIAS) {
                float4 bo = reinterpret_cast<const float4*>(b_out)[slot];
                o.x += bo.x; o.y += bo.y; o.z += bo.z; o.w += bo.w;
            }
            reinterpret_cast<float4*>(AGG + (size_t)row * F)[slot] = o;
        }
    }
}

// ---------------- edge scatter: AGG[col] += H[row] * dinv[row]*dinv[col] ----
template<int F>
__global__ __launch_bounds__(256) void k_scatter(
    const int* __restrict__ row, const int* __restrict__ col,
    const float* __restrict__ dinv,
    const float* __restrict__ H, float* __restrict__ AGG, int total)
{
    constexpr int CH = F / 4;              // float4 chunks per edge (pow2)
    int idx = blockIdx.x * 256 + threadIdx.x;
    if (idx >= total) return;
    int e = idx / CH;
    int c = idx - e * CH;
    int r = row[e];
    int t = col[e];
    float nrm = dinv[r] * dinv[t];
    float4 h = reinterpret_cast<const float4*>(H + (size_t)r * F)[c];
    float* dst = AGG + (size_t)t * F + c * 4;
    unsafeAtomicAdd(dst + 0, h.x * nrm);
    unsafeAtomicAdd(dst + 1, h.y * nrm);
    unsafeAtomicAdd(dst + 2, h.z * nrm);
    unsafeAtomicAdd(dst + 3, h.w * nrm);
}

// ---------------- launch ----------------

extern "C" void kernel_launch(void* const* d_in, const int* in_sizes, int n_in,
                              void* d_out, int out_size, void* d_ws, size_t ws_size,
                              hipStream_t stream) {
    const float* x  = (const float*)d_in[0];
    const int*   ei = (const int*)  d_in[1];
    const float* W1 = (const float*)d_in[2];
    const float* b1 = (const float*)d_in[3];
    const float* W2 = (const float*)d_in[4];
    const float* b2 = (const float*)d_in[5];
    float* out = (float*)d_out;

    const int* row = ei;             // edge_index[0] = sources
    const int* col = ei + N_EDGES;   // edge_index[1] = targets

    float* ws   = (float*)d_ws;
    float* dinv = ws;                                       // N floats
    float* bufA = ws + ((N_NODES + 255) & ~255);            // N*128 (h1, then h2)
    float* bufB = bufA + (size_t)N_NODES * 128;             // N*128 (agg1)

    // 1) degrees -> dinv
    k_init_deg <<<(N_NODES + 255) / 256, 256, 0, stream>>>(dinv, N_NODES);
    k_count_deg<<<(N_EDGES + 255) / 256, 256, 0, stream>>>(col, dinv, N_EDGES);
    k_dinv     <<<(N_NODES + 255) / 256, 256, 0, stream>>>(dinv, N_NODES);

    // 2) h1 = x@W1 ; agg1 = h1*dinv^2 (self-loop init)
    //    F=128, C=32, R=2 -> TX=4, TY=64, 128 rows/block
    k_gemm<128, 32, 2, false, false><<<(N_NODES + 127) / 128, 256, 0, stream>>>(
        x, W1, nullptr, nullptr, dinv, bufA, bufB, N_NODES);

    // 3) agg1[col] += h1[row]*norm over all edges
    int tot1 = N_EDGES * 32;
    k_scatter<128><<<(tot1 + 255) / 256, 256, 0, stream>>>(row, col, dinv, bufA, bufB, tot1);

    // 4) h2 = relu(agg1+b1)@W2 ; out = h2*dinv^2 + b2 (self-loop + bias init)
    //    F=64, C=16, R=2 -> TX=4, TY=64, 128 rows/block
    k_gemm<64, 16, 2, true, true><<<(N_NODES + 127) / 128, 256, 0, stream>>>(
        bufB, W2, b1, b2, dinv, bufA, out, N_NODES);

    // 5) out[col] += h2[row]*norm
    int tot2 = N_EDGES * 16;
    k_scatter<64><<<(tot2 + 255) / 256, 256, 0, stream>>>(row, col, dinv, bufA, out, tot2);
}

// Round 2
// 818.089 us; speedup vs baseline: 5.1794x; 5.1794x over previous
//
#include <hip/hip_runtime.h>

#define N_NODES 100000
#define N_EDGES 1600000
#define K_DIM   128   // both layers contract over 128

// ---------------- CSR build: count, scan(+dinv), fill ----------------

__global__ __launch_bounds__(256) void k_zero(int* p, int n) {
    int i = blockIdx.x * 256 + threadIdx.x;
    if (i < n) p[i] = 0;
}

__global__ __launch_bounds__(256) void k_count(const int* __restrict__ col,
                                               int* __restrict__ counts, int e) {
    int i = blockIdx.x * 256 + threadIdx.x;
    if (i < e) atomicAdd(&counts[col[i]], 1);
}

// Single-block exclusive scan over counts[n] -> rowptr; counts becomes cursor
// (copy of rowptr); dinv[i] = rsqrt(1 + indeg) (self-loop included).
__global__ __launch_bounds__(256) void k_scan(int* __restrict__ counts,
                                              int* __restrict__ rowptr,
                                              float* __restrict__ dinv, int n) {
    __shared__ int sums[256];
    int t = threadIdx.x;
    int per = (n + 255) >> 8;
    int lo = t * per, hi = min(lo + per, n);
    int s = 0;
    for (int i = lo; i < hi; ++i) s += counts[i];
    sums[t] = s;
    __syncthreads();
    for (int off = 1; off < 256; off <<= 1) {   // Hillis-Steele inclusive
        int v = (t >= off) ? sums[t - off] : 0;
        __syncthreads();
        sums[t] += v;
        __syncthreads();
    }
    int base = (t == 0) ? 0 : sums[t - 1];
    for (int i = lo; i < hi; ++i) {
        int c = counts[i];
        rowptr[i] = base;
        counts[i] = base;                        // cursor for fill
        dinv[i] = rsqrtf(1.0f + (float)c);
        base += c;
    }
    if (t == 255) rowptr[n] = base;              // == E
}

__global__ __launch_bounds__(256) void k_fill(const int* __restrict__ row,
                                              const int* __restrict__ col,
                                              int* __restrict__ cursor,
                                              int* __restrict__ srows, int e) {
    int i = blockIdx.x * 256 + threadIdx.x;
    if (i < e) {
        int pos = atomicAdd(&cursor[col[i]], 1);
        srows[pos] = row[i];
    }
}

// ---------------- dense transform (fp32 VALU GEMM, W in LDS) ----------------
// A:[nrows,128] @ B:[128,F] -> H:[nrows,F].  RELU_IN: A-elem := relu(A+b_in).
template<int F, int C, int R, bool RELU_IN>
__global__ __launch_bounds__(256) void k_gemm(
    const float* __restrict__ A, const float* __restrict__ B,
    const float* __restrict__ b_in, float* __restrict__ H, int nrows)
{
    constexpr int K  = K_DIM;
    constexpr int TX = F / C;
    constexpr int TY = 256 / TX;
    constexpr int ROWS = TY * R;
    constexpr int SL = C / 4;
    static_assert(TX * C == F && TX * TY == 256, "layout");

    __shared__ float Blds[K * F];
    for (int i = threadIdx.x; i < K * F / 4; i += 256)
        reinterpret_cast<float4*>(Blds)[i] = reinterpret_cast<const float4*>(B)[i];
    __syncthreads();

    const int tx = threadIdx.x % TX;
    const int ty = threadIdx.x / TX;
    const int row0 = blockIdx.x * ROWS + ty * R;

    float acc[R][C];
#pragma unroll
    for (int r = 0; r < R; ++r)
#pragma unroll
        for (int j = 0; j < C; ++j) acc[r][j] = 0.0f;

    for (int k4 = 0; k4 < K / 4; ++k4) {
        float4 a4[R];
        float4 bin;
        if constexpr (RELU_IN) bin = reinterpret_cast<const float4*>(b_in)[k4];
#pragma unroll
        for (int r = 0; r < R; ++r) {
            int row = row0 + r;
            if (row < nrows) {
                float4 v = reinterpret_cast<const float4*>(A + (size_t)row * K)[k4];
                if constexpr (RELU_IN) {
                    v.x = fmaxf(v.x + bin.x, 0.0f);
                    v.y = fmaxf(v.y + bin.y, 0.0f);
                    v.z = fmaxf(v.z + bin.z, 0.0f);
                    v.w = fmaxf(v.w + bin.w, 0.0f);
                }
                a4[r] = v;
            } else {
                a4[r] = make_float4(0.f, 0.f, 0.f, 0.f);
            }
        }
#pragma unroll
        for (int kk = 0; kk < 4; ++kk) {
            const int k = k4 * 4 + kk;
            const float4* Brow = reinterpret_cast<const float4*>(Blds + k * F);
#pragma unroll
            for (int s = 0; s < SL; ++s) {
                float4 b = Brow[s * TX + tx];
#pragma unroll
                for (int r = 0; r < R; ++r) {
                    float a = (kk == 0) ? a4[r].x : (kk == 1) ? a4[r].y
                            : (kk == 2) ? a4[r].z : a4[r].w;
                    acc[r][s*4+0] = fmaf(a, b.x, acc[r][s*4+0]);
                    acc[r][s*4+1] = fmaf(a, b.y, acc[r][s*4+1]);
                    acc[r][s*4+2] = fmaf(a, b.z, acc[r][s*4+2]);
                    acc[r][s*4+3] = fmaf(a, b.w, acc[r][s*4+3]);
                }
            }
        }
    }

#pragma unroll
    for (int r = 0; r < R; ++r) {
        int row = row0 + r;
        if (row >= nrows) continue;
#pragma unroll
        for (int s = 0; s < SL; ++s) {
            int slot = s * TX + tx;
            float4 v = make_float4(acc[r][s*4+0], acc[r][s*4+1],
                                   acc[r][s*4+2], acc[r][s*4+3]);
            reinterpret_cast<float4*>(H + (size_t)row * F)[slot] = v;
        }
    }
}

// ---------------- gather: one wave per destination node -------------------
// OUT[i] = sum_{e: col(e)=i} H[row(e)]*dinv[row]*dinv[i] + H[i]*dinv[i]^2 (+bias)
template<int F, bool OUT_BIAS>
__global__ __launch_bounds__(256) void k_gather(
    const int* __restrict__ rowptr, const int* __restrict__ srows,
    const float* __restrict__ dinv, const float* __restrict__ H,
    const float* __restrict__ bias, float* __restrict__ OUT, int n)
{
    int w = blockIdx.x * 4 + (threadIdx.x >> 6);   // node = wave id
    if (w >= n) return;
    int lane = threadIdx.x & 63;
    float di = dinv[w];
    int s = rowptr[w], e = rowptr[w + 1];

    if constexpr (F == 128) {
        const float2* Hp = reinterpret_cast<const float2*>(H);
        float2 acc = Hp[(size_t)w * 64 + lane];    // self row
        float dd = di * di;
        acc.x *= dd; acc.y *= dd;
        int r_next = (s < e) ? srows[s] : 0;
        for (int k = s; k < e; ++k) {
            int r = r_next;
            if (k + 1 < e) r_next = srows[k + 1];
            float nrm = dinv[r] * di;
            float2 hv = Hp[(size_t)r * 64 + lane];
            acc.x = fmaf(hv.x, nrm, acc.x);
            acc.y = fmaf(hv.y, nrm, acc.y);
        }
        reinterpret_cast<float2*>(OUT)[(size_t)w * 64 + lane] = acc;
    } else {
        float acc = H[(size_t)w * F + lane] * di * di;  // self row
        int r_next = (s < e) ? srows[s] : 0;
        for (int k = s; k < e; ++k) {
            int r = r_next;
            if (k + 1 < e) r_next = srows[k + 1];
            float nrm = dinv[r] * di;
            acc = fmaf(H[(size_t)r * F + lane], nrm, acc);
        }
        if constexpr (OUT_BIAS) acc += bias[lane];
        OUT[(size_t)w * F + lane] = acc;
    }
}

// ---------------- launch ----------------

extern "C" void kernel_launch(void* const* d_in, const int* in_sizes, int n_in,
                              void* d_out, int out_size, void* d_ws, size_t ws_size,
                              hipStream_t stream) {
    const float* x  = (const float*)d_in[0];
    const int*   ei = (const int*)  d_in[1];
    const float* W1 = (const float*)d_in[2];
    const float* b1 = (const float*)d_in[3];
    const float* W2 = (const float*)d_in[4];
    const float* b2 = (const float*)d_in[5];
    float* out = (float*)d_out;

    const int* row = ei;             // sources
    const int* col = ei + N_EDGES;   // targets

    // workspace layout (all 4B elems, 256-elem aligned)
    char* ws = (char*)d_ws;
    int*   counts = (int*)ws;                                  // N (then cursor)
    int*   rowptr = counts + ((N_NODES + 256) & ~255);         // N+1
    float* dinv   = (float*)(rowptr + ((N_NODES + 256) & ~255)); // N
    int*   srows  = (int*)(dinv + ((N_NODES + 255) & ~255));   // E
    float* bufH   = (float*)(srows + ((N_EDGES + 255) & ~255)); // N*128 (h1,h2)
    float* bufAgg = bufH + (size_t)N_NODES * 128;              // N*128 (agg1)

    const int GB_N = (N_NODES + 255) / 256;
    const int GB_E = (N_EDGES + 255) / 256;

    // 1) CSR by destination + dinv
    k_zero <<<GB_N, 256, 0, stream>>>(counts, N_NODES);
    k_count<<<GB_E, 256, 0, stream>>>(col, counts, N_EDGES);
    k_scan <<<1,    256, 0, stream>>>(counts, rowptr, dinv, N_NODES);
    k_fill <<<GB_E, 256, 0, stream>>>(row, col, counts, srows, N_EDGES);

    // 2) h1 = x@W1
    k_gemm<128, 32, 2, false><<<(N_NODES + 127) / 128, 256, 0, stream>>>(
        x, W1, nullptr, bufH, N_NODES);

    // 3) agg1 = gather(h1) (self-loop fused)
    k_gather<128, false><<<(N_NODES + 3) / 4, 256, 0, stream>>>(
        rowptr, srows, dinv, bufH, nullptr, bufAgg, N_NODES);

    // 4) h2 = relu(agg1+b1)@W2
    k_gemm<64, 16, 2, true><<<(N_NODES + 127) / 128, 256, 0, stream>>>(
        bufAgg, W2, b1, bufH, N_NODES);

    // 5) out = gather(h2) + b2
    k_gather<64, true><<<(N_NODES + 3) / 4, 256, 0, stream>>>(
        rowptr, srows, dinv, bufH, b2, out, N_NODES);
}

// Round 3
// 545.146 us; speedup vs baseline: 7.7726x; 1.5007x over previous
//
#include <hip/hip_runtime.h>

#define N_NODES 100000
#define N_EDGES 1600000
#define K_DIM   128   // both layers contract over 128

#define SCAN_CHUNK 1024
#define NB_SCAN ((N_NODES + SCAN_CHUNK - 1) / SCAN_CHUNK)   // 98

// ---------------- CSR build: count, hierarchical scan, fill ----------------

__global__ __launch_bounds__(256) void k_zero(int* p, int n) {
    int i = blockIdx.x * 256 + threadIdx.x;
    if (i < n) p[i] = 0;
}

__global__ __launch_bounds__(256) void k_count(const int* __restrict__ col,
                                               int* __restrict__ counts, int e) {
    int i = blockIdx.x * 256 + threadIdx.x;
    if (i < e) atomicAdd(&counts[col[i]], 1);
}

// pass 1: per-block (1024-elem) sums
__global__ __launch_bounds__(256) void k_scan1(const int* __restrict__ counts,
                                               int* __restrict__ bsums, int n) {
    int t = threadIdx.x;
    int i0 = blockIdx.x * SCAN_CHUNK + t * 4;
    int s = 0;
    if (i0 + 3 < n) {
        int4 c = *reinterpret_cast<const int4*>(counts + i0);
        s = c.x + c.y + c.z + c.w;
    } else {
        for (int j = 0; j < 4; ++j) if (i0 + j < n) s += counts[i0 + j];
    }
    for (int off = 32; off; off >>= 1) s += __shfl_down(s, off, 64);
    __shared__ int wsum[4];
    if ((t & 63) == 0) wsum[t >> 6] = s;
    __syncthreads();
    if (t == 0) bsums[blockIdx.x] = wsum[0] + wsum[1] + wsum[2] + wsum[3];
}

// pass 2: single tiny block scans the 98 block sums -> exclusive offsets;
// also writes rowptr[n] = E total.
__global__ __launch_bounds__(128) void k_scan2(int* __restrict__ bsums,
                                               int* __restrict__ rowptr,
                                               int nb, int n) {
    __shared__ int sm[128];
    int t = threadIdx.x;
    sm[t] = (t < nb) ? bsums[t] : 0;
    __syncthreads();
    for (int off = 1; off < 128; off <<= 1) {
        int u = (t >= off) ? sm[t - off] : 0;
        __syncthreads();
        sm[t] += u;
        __syncthreads();
    }
    if (t < nb) bsums[t] = (t == 0) ? 0 : sm[t - 1];
    if (t == 127) rowptr[n] = sm[127];
}

// pass 3: per-block exclusive scan + block offset; writes rowptr, cursor
// (same values, consumed by k_fill), and dinv = rsqrt(1 + indeg).
__global__ __launch_bounds__(256) void k_scan3(int* __restrict__ counts,
                                               const int* __restrict__ bsums,
                                               int* __restrict__ rowptr,
                                               float* __restrict__ dinv, int n) {
    int t = threadIdx.x;
    int i0 = blockIdx.x * SCAN_CHUNK + t * 4;
    int4 c = make_int4(0, 0, 0, 0);
    if (i0 + 3 < n) {
        c = *reinterpret_cast<const int4*>(counts + i0);
    } else {
        if (i0 + 0 < n) c.x = counts[i0 + 0];
        if (i0 + 1 < n) c.y = counts[i0 + 1];
        if (i0 + 2 < n) c.z = counts[i0 + 2];
    }
    int tot = c.x + c.y + c.z + c.w;
    __shared__ int sm[256];
    sm[t] = tot;
    __syncthreads();
    for (int off = 1; off < 256; off <<= 1) {
        int u = (t >= off) ? sm[t - off] : 0;
        __syncthreads();
        sm[t] += u;
        __syncthreads();
    }
    int base = bsums[blockIdx.x] + ((t == 0) ? 0 : sm[t - 1]);
    int o0 = base, o1 = o0 + c.x, o2 = o1 + c.y, o3 = o2 + c.z;
    if (i0 + 3 < n) {
        *reinterpret_cast<int4*>(rowptr + i0) = make_int4(o0, o1, o2, o3);
        *reinterpret_cast<int4*>(counts + i0) = make_int4(o0, o1, o2, o3); // cursor
        float4 d = make_float4(rsqrtf(1.f + (float)c.x), rsqrtf(1.f + (float)c.y),
                               rsqrtf(1.f + (float)c.z), rsqrtf(1.f + (float)c.w));
        *reinterpret_cast<float4*>(dinv + i0) = d;
    } else {
        int oo[4] = {o0, o1, o2, o3};
        int cc[4] = {c.x, c.y, c.z, c.w};
        for (int j = 0; j < 4; ++j) if (i0 + j < n) {
            rowptr[i0 + j] = oo[j];
            counts[i0 + j] = oo[j];
            dinv[i0 + j] = rsqrtf(1.f + (float)cc[j]);
        }
    }
}

__global__ __launch_bounds__(256) void k_fill(const int* __restrict__ row,
                                              const int* __restrict__ col,
                                              int* __restrict__ cursor,
                                              int* __restrict__ srows, int e) {
    int i = blockIdx.x * 256 + threadIdx.x;
    if (i < e) {
        int pos = atomicAdd(&cursor[col[i]], 1);
        srows[pos] = row[i];
    }
}

// ---------------- dense transform (fp32 VALU GEMM, W in LDS) ----------------
// A:[nrows,128] @ B:[128,F] -> H:[nrows,F].  RELU_IN: A-elem := relu(A+b_in).
template<int F, int C, int R, bool RELU_IN>
__global__ __launch_bounds__(256) void k_gemm(
    const float* __restrict__ A, const float* __restrict__ B,
    const float* __restrict__ b_in, float* __restrict__ H, int nrows)
{
    constexpr int K  = K_DIM;
    constexpr int TX = F / C;
    constexpr int TY = 256 / TX;
    constexpr int ROWS = TY * R;
    constexpr int SL = C / 4;
    static_assert(TX * C == F && TX * TY == 256, "layout");

    __shared__ float Blds[K * F];
    for (int i = threadIdx.x; i < K * F / 4; i += 256)
        reinterpret_cast<float4*>(Blds)[i] = reinterpret_cast<const float4*>(B)[i];
    __syncthreads();

    const int tx = threadIdx.x % TX;
    const int ty = threadIdx.x / TX;
    const int row0 = blockIdx.x * ROWS + ty * R;

    float acc[R][C];
#pragma unroll
    for (int r = 0; r < R; ++r)
#pragma unroll
        for (int j = 0; j < C; ++j) acc[r][j] = 0.0f;

    for (int k4 = 0; k4 < K / 4; ++k4) {
        float4 a4[R];
        float4 bin;
        if constexpr (RELU_IN) bin = reinterpret_cast<const float4*>(b_in)[k4];
#pragma unroll
        for (int r = 0; r < R; ++r) {
            int row = row0 + r;
            if (row < nrows) {
                float4 v = reinterpret_cast<const float4*>(A + (size_t)row * K)[k4];
                if constexpr (RELU_IN) {
                    v.x = fmaxf(v.x + bin.x, 0.0f);
                    v.y = fmaxf(v.y + bin.y, 0.0f);
                    v.z = fmaxf(v.z + bin.z, 0.0f);
                    v.w = fmaxf(v.w + bin.w, 0.0f);
                }
                a4[r] = v;
            } else {
                a4[r] = make_float4(0.f, 0.f, 0.f, 0.f);
            }
        }
#pragma unroll
        for (int kk = 0; kk < 4; ++kk) {
            const int k = k4 * 4 + kk;
            const float4* Brow = reinterpret_cast<const float4*>(Blds + k * F);
#pragma unroll
            for (int s = 0; s < SL; ++s) {
                float4 b = Brow[s * TX + tx];
#pragma unroll
                for (int r = 0; r < R; ++r) {
                    float a = (kk == 0) ? a4[r].x : (kk == 1) ? a4[r].y
                            : (kk == 2) ? a4[r].z : a4[r].w;
                    acc[r][s*4+0] = fmaf(a, b.x, acc[r][s*4+0]);
                    acc[r][s*4+1] = fmaf(a, b.y, acc[r][s*4+1]);
                    acc[r][s*4+2] = fmaf(a, b.z, acc[r][s*4+2]);
                    acc[r][s*4+3] = fmaf(a, b.w, acc[r][s*4+3]);
                }
            }
        }
    }

#pragma unroll
    for (int r = 0; r < R; ++r) {
        int row = row0 + r;
        if (row >= nrows) continue;
#pragma unroll
        for (int s = 0; s < SL; ++s) {
            int slot = s * TX + tx;
            float4 v = make_float4(acc[r][s*4+0], acc[r][s*4+1],
                                   acc[r][s*4+2], acc[r][s*4+3]);
            reinterpret_cast<float4*>(H + (size_t)row * F)[slot] = v;
        }
    }
}

// ---------------- gather: one wave per destination node -------------------
// OUT[i] = sum_{e: col(e)=i} H[row(e)]*dinv[row]*dinv[i] + H[i]*dinv[i]^2 (+bias)
template<int F, bool OUT_BIAS>
__global__ __launch_bounds__(256) void k_gather(
    const int* __restrict__ rowptr, const int* __restrict__ srows,
    const float* __restrict__ dinv, const float* __restrict__ H,
    const float* __restrict__ bias, float* __restrict__ OUT, int n)
{
    int w = blockIdx.x * 4 + (threadIdx.x >> 6);   // node = wave id
    if (w >= n) return;
    int lane = threadIdx.x & 63;
    float di = dinv[w];
    int s = rowptr[w], e = rowptr[w + 1];

    if constexpr (F == 128) {
        const float2* Hp = reinterpret_cast<const float2*>(H);
        float2 acc = Hp[(size_t)w * 64 + lane];    // self row
        float dd = di * di;
        acc.x *= dd; acc.y *= dd;
        int r_next = (s < e) ? srows[s] : 0;
        for (int k = s; k < e; ++k) {
            int r = r_next;
            if (k + 1 < e) r_next = srows[k + 1];
            float nrm = dinv[r] * di;
            float2 hv = Hp[(size_t)r * 64 + lane];
            acc.x = fmaf(hv.x, nrm, acc.x);
            acc.y = fmaf(hv.y, nrm, acc.y);
        }
        reinterpret_cast<float2*>(OUT)[(size_t)w * 64 + lane] = acc;
    } else {
        float acc = H[(size_t)w * F + lane] * di * di;  // self row
        int r_next = (s < e) ? srows[s] : 0;
        for (int k = s; k < e; ++k) {
            int r = r_next;
            if (k + 1 < e) r_next = srows[k + 1];
            float nrm = dinv[r] * di;
            acc = fmaf(H[(size_t)r * F + lane], nrm, acc);
        }
        if constexpr (OUT_BIAS) acc += bias[lane];
        OUT[(size_t)w * F + lane] = acc;
    }
}

// ---------------- launch ----------------

extern "C" void kernel_launch(void* const* d_in, const int* in_sizes, int n_in,
                              void* d_out, int out_size, void* d_ws, size_t ws_size,
                              hipStream_t stream) {
    const float* x  = (const float*)d_in[0];
    const int*   ei = (const int*)  d_in[1];
    const float* W1 = (const float*)d_in[2];
    const float* b1 = (const float*)d_in[3];
    const float* W2 = (const float*)d_in[4];
    const float* b2 = (const float*)d_in[5];
    float* out = (float*)d_out;

    const int* row = ei;             // sources
    const int* col = ei + N_EDGES;   // targets

    // workspace layout (all 4B elems, 256-elem aligned)
    char* ws = (char*)d_ws;
    int*   counts = (int*)ws;                                    // N (then cursor)
    int*   rowptr = counts + ((N_NODES + 256) & ~255);           // N+1
    float* dinv   = (float*)(rowptr + ((N_NODES + 256) & ~255)); // N
    int*   bsums  = (int*)(dinv + ((N_NODES + 255) & ~255));     // NB_SCAN
    int*   srows  = bsums + 256;                                 // E
    float* bufH   = (float*)(srows + ((N_EDGES + 255) & ~255));  // N*128 (h1,h2)
    float* bufAgg = bufH + (size_t)N_NODES * 128;                // N*128 (agg1)

    const int GB_N = (N_NODES + 255) / 256;
    const int GB_E = (N_EDGES + 255) / 256;

    // 1) CSR by destination + dinv
    k_zero <<<GB_N, 256, 0, stream>>>(counts, N_NODES);
    k_count<<<GB_E, 256, 0, stream>>>(col, counts, N_EDGES);
    k_scan1<<<NB_SCAN, 256, 0, stream>>>(counts, bsums, N_NODES);
    k_scan2<<<1, 128, 0, stream>>>(bsums, rowptr, NB_SCAN, N_NODES);
    k_scan3<<<NB_SCAN, 256, 0, stream>>>(counts, bsums, rowptr, dinv, N_NODES);
    k_fill <<<GB_E, 256, 0, stream>>>(row, col, counts, srows, N_EDGES);

    // 2) h1 = x@W1
    k_gemm<128, 32, 2, false><<<(N_NODES + 127) / 128, 256, 0, stream>>>(
        x, W1, nullptr, bufH, N_NODES);

    // 3) agg1 = gather(h1) (self-loop fused)
    k_gather<128, false><<<(N_NODES + 3) / 4, 256, 0, stream>>>(
        rowptr, srows, dinv, bufH, nullptr, bufAgg, N_NODES);

    // 4) h2 = relu(agg1+b1)@W2
    k_gemm<64, 16, 2, true><<<(N_NODES + 127) / 128, 256, 0, stream>>>(
        bufAgg, W2, b1, bufH, N_NODES);

    // 5) out = gather(h2) + b2
    k_gather<64, true><<<(N_NODES + 3) / 4, 256, 0, stream>>>(
        rowptr, srows, dinv, bufH, b2, out, N_NODES);
}

// Round 4
// 372.749 us; speedup vs baseline: 11.3675x; 1.4625x over previous
//
#include <hip/hip_runtime.h>

#define N_NODES 100000
#define N_EDGES 1600000
#define K_DIM   128

#define CHUNK_LG 10
#define CHUNK    1024                                    // nodes per bucket
#define NBKT     ((N_NODES + CHUNK - 1) / CHUNK)         // 98
#define CAP      18432                                   // >> 16384 avg + 16 sigma
#define EPB      4096                                    // edges per phase-A block
#define NBLK_A   ((N_EDGES + EPB - 1) / EPB)             // 391

// ---------------- CSR build, bucketed ----------------

__global__ __launch_bounds__(128) void k_zero_small(int* p, int n) {
    int i = threadIdx.x;
    if (i < n) p[i] = 0;
}

// Phase A: partition edges into NBKT bucket regions as packed 4B entries.
__global__ __launch_bounds__(256) void k_bucket(const int* __restrict__ row,
                                                const int* __restrict__ col,
                                                int* __restrict__ gcur,
                                                int* __restrict__ pairs) {
    __shared__ int hist[NBKT], sbase[NBKT], lcur[NBKT];
    int t = threadIdx.x;
    if (t < NBKT) { hist[t] = 0; lcur[t] = 0; }
    __syncthreads();
    int base = blockIdx.x * EPB;
    int myb[16], myp[16];
#pragma unroll
    for (int j = 0; j < 16; ++j) {
        int i = base + t + j * 256;
        int b = -1, p = 0;
        if (i < N_EDGES) {
            int r = row[i], c = col[i];
            b = c >> CHUNK_LG;
            p = ((c & (CHUNK - 1)) << 17) | r;     // row < 2^17
            atomicAdd(&hist[b], 1);
        }
        myb[j] = b; myp[j] = p;
    }
    __syncthreads();
    if (t < NBKT) {
        int c = hist[t];
        sbase[t] = c ? atomicAdd(&gcur[t], c) : 0;
    }
    __syncthreads();
#pragma unroll
    for (int j = 0; j < 16; ++j) {
        int b = myb[j];
        if (b >= 0) {
            int pos = sbase[b] + atomicAdd(&lcur[b], 1);
            pairs[b * CAP + pos] = myp[j];
        }
    }
}

// exclusive scan of 98 bucket counts -> gbase; rowptr[N] = E
__global__ __launch_bounds__(128) void k_bases(const int* __restrict__ gcur,
                                               int* __restrict__ gbase,
                                               int* __restrict__ rowptr) {
    __shared__ int sm[128];
    int t = threadIdx.x;
    int v = (t < NBKT) ? gcur[t] : 0;
    sm[t] = v;
    __syncthreads();
    for (int off = 1; off < 128; off <<= 1) {
        int u = (t >= off) ? sm[t - off] : 0;
        __syncthreads();
        sm[t] += u;
        __syncthreads();
    }
    if (t < NBKT) gbase[t] = sm[t] - v;
    if (t == 127) rowptr[N_NODES] = sm[127];
}

// Phase B: one block per bucket; local hist+scan -> rowptr/dinv; fill srows.
__global__ __launch_bounds__(256) void k_fillB(const int* __restrict__ gcur,
                                               const int* __restrict__ gbase,
                                               const int* __restrict__ pairs,
                                               int* __restrict__ rowptr,
                                               float* __restrict__ dinv,
                                               int* __restrict__ srows) {
    __shared__ int deg[CHUNK];
    __shared__ int curs[CHUNK];
    __shared__ int psum[256];
    int b = blockIdx.x, t = threadIdx.x;
    int nbase = b << CHUNK_LG;
    int nn = min(CHUNK, N_NODES - nbase);
    int cnt = gcur[b];
    int gb = gbase[b];
    const int* mp = pairs + b * CAP;

    for (int i = t; i < CHUNK; i += 256) deg[i] = 0;
    __syncthreads();
    for (int i = t; i < cnt; i += 256) atomicAdd(&deg[mp[i] >> 17], 1);
    __syncthreads();

    int i0 = t * 4;
    int d0 = deg[i0], d1 = deg[i0 + 1], d2 = deg[i0 + 2], d3 = deg[i0 + 3];
    int s4 = d0 + d1 + d2 + d3;
    psum[t] = s4;
    __syncthreads();
    for (int off = 1; off < 256; off <<= 1) {
        int u = (t >= off) ? psum[t - off] : 0;
        __syncthreads();
        psum[t] += u;
        __syncthreads();
    }
    int ex = gb + psum[t] - s4;
    int o0 = ex, o1 = o0 + d0, o2 = o1 + d1, o3 = o2 + d2;
    curs[i0] = o0; curs[i0 + 1] = o1; curs[i0 + 2] = o2; curs[i0 + 3] = o3;
    if (i0 + 3 < nn) {
        *reinterpret_cast<int4*>(rowptr + nbase + i0) = make_int4(o0, o1, o2, o3);
        float4 dv = make_float4(rsqrtf(1.f + (float)d0), rsqrtf(1.f + (float)d1),
                                rsqrtf(1.f + (float)d2), rsqrtf(1.f + (float)d3));
        *reinterpret_cast<float4*>(dinv + nbase + i0) = dv;
    } else {
        int oo[4] = {o0, o1, o2, o3};
        int dd[4] = {d0, d1, d2, d3};
        for (int j = 0; j < 4; ++j) if (i0 + j < nn) {
            rowptr[nbase + i0 + j] = oo[j];
            dinv[nbase + i0 + j] = rsqrtf(1.f + (float)dd[j]);
        }
    }
    __syncthreads();
    for (int i = t; i < cnt; i += 256) {
        int v = mp[i];
        int pos = atomicAdd(&curs[v >> 17], 1);
        srows[pos] = v & 0x1FFFF;
    }
}

// ---------------- dense transform (fp32 VALU GEMM, W in LDS) ----------------
template<int F, int C, int R, bool RELU_IN>
__global__ __launch_bounds__(256) void k_gemm(
    const float* __restrict__ A, const float* __restrict__ B,
    const float* __restrict__ b_in, float* __restrict__ H, int nrows)
{
    constexpr int K  = K_DIM;
    constexpr int TX = F / C;
    constexpr int TY = 256 / TX;
    constexpr int ROWS = TY * R;
    constexpr int SL = C / 4;
    static_assert(TX * C == F && TX * TY == 256, "layout");

    __shared__ float Blds[K * F];
    for (int i = threadIdx.x; i < K * F / 4; i += 256)
        reinterpret_cast<float4*>(Blds)[i] = reinterpret_cast<const float4*>(B)[i];
    __syncthreads();

    const int tx = threadIdx.x % TX;
    const int ty = threadIdx.x / TX;
    const int row0 = blockIdx.x * ROWS + ty * R;

    float acc[R][C];
#pragma unroll
    for (int r = 0; r < R; ++r)
#pragma unroll
        for (int j = 0; j < C; ++j) acc[r][j] = 0.0f;

    for (int k4 = 0; k4 < K / 4; ++k4) {
        float4 a4[R];
        float4 bin;
        if constexpr (RELU_IN) bin = reinterpret_cast<const float4*>(b_in)[k4];
#pragma unroll
        for (int r = 0; r < R; ++r) {
            int row = row0 + r;
            if (row < nrows) {
                float4 v = reinterpret_cast<const float4*>(A + (size_t)row * K)[k4];
                if constexpr (RELU_IN) {
                    v.x = fmaxf(v.x + bin.x, 0.0f);
                    v.y = fmaxf(v.y + bin.y, 0.0f);
                    v.z = fmaxf(v.z + bin.z, 0.0f);
                    v.w = fmaxf(v.w + bin.w, 0.0f);
                }
                a4[r] = v;
            } else {
                a4[r] = make_float4(0.f, 0.f, 0.f, 0.f);
            }
        }
#pragma unroll
        for (int kk = 0; kk < 4; ++kk) {
            const int k = k4 * 4 + kk;
            const float4* Brow = reinterpret_cast<const float4*>(Blds + k * F);
#pragma unroll
            for (int s = 0; s < SL; ++s) {
                float4 b = Brow[s * TX + tx];
#pragma unroll
                for (int r = 0; r < R; ++r) {
                    float a = (kk == 0) ? a4[r].x : (kk == 1) ? a4[r].y
                            : (kk == 2) ? a4[r].z : a4[r].w;
                    acc[r][s*4+0] = fmaf(a, b.x, acc[r][s*4+0]);
                    acc[r][s*4+1] = fmaf(a, b.y, acc[r][s*4+1]);
                    acc[r][s*4+2] = fmaf(a, b.z, acc[r][s*4+2]);
                    acc[r][s*4+3] = fmaf(a, b.w, acc[r][s*4+3]);
                }
            }
        }
    }

#pragma unroll
    for (int r = 0; r < R; ++r) {
        int row = row0 + r;
        if (row >= nrows) continue;
#pragma unroll
        for (int s = 0; s < SL; ++s) {
            int slot = s * TX + tx;
            float4 v = make_float4(acc[r][s*4+0], acc[r][s*4+1],
                                   acc[r][s*4+2], acc[r][s*4+3]);
            reinterpret_cast<float4*>(H + (size_t)row * F)[slot] = v;
        }
    }
}

// ---------------- gather: one wave per destination node -------------------
// float4/lane; one wave-load covers GR rows at once; 2 loads in flight.
template<int F, bool OUT_BIAS>
__global__ __launch_bounds__(256) void k_gather(
    const int* __restrict__ rowptr, const int* __restrict__ srows,
    const float* __restrict__ dinv, const float* __restrict__ H,
    const float* __restrict__ bias, float* __restrict__ OUT, int n)
{
    constexpr int LPR = F / 4;     // lanes per row (32 or 16)
    constexpr int GR  = 64 / LPR;  // rows covered per wave-load (2 or 4)
    int w = blockIdx.x * 4 + (threadIdx.x >> 6);
    if (w >= n) return;
    int lane = threadIdx.x & 63;
    int g = lane / LPR;            // row group within wave
    int c = lane % LPR;            // float4 slot within row
    float di = dinv[w];
    int s = rowptr[w], e = rowptr[w + 1];
    const float4* Hp = reinterpret_cast<const float4*>(H);

    float4 hv = Hp[(size_t)w * LPR + c];           // self row (broadcast lines)
    float sw = (g == 0) ? di * di : 0.f;
    float4 acc;
    acc.x = hv.x * sw; acc.y = hv.y * sw; acc.z = hv.z * sw; acc.w = hv.w * sw;

    for (int k = s; k < e; k += 2 * GR) {
        int k0 = k + g, k1 = k + GR + g;
        int kk0 = min(k0, e - 1), kk1 = min(k1, e - 1);
        int r0 = srows[kk0], r1 = srows[kk1];
        float w0 = (k0 < e) ? dinv[r0] * di : 0.f;
        float w1 = (k1 < e) ? dinv[r1] * di : 0.f;
        float4 h0 = Hp[(size_t)r0 * LPR + c];
        float4 h1 = Hp[(size_t)r1 * LPR + c];
        acc.x = fmaf(h0.x, w0, acc.x); acc.y = fmaf(h0.y, w0, acc.y);
        acc.z = fmaf(h0.z, w0, acc.z); acc.w = fmaf(h0.w, w0, acc.w);
        acc.x = fmaf(h1.x, w1, acc.x); acc.y = fmaf(h1.y, w1, acc.y);
        acc.z = fmaf(h1.z, w1, acc.z); acc.w = fmaf(h1.w, w1, acc.w);
    }

#pragma unroll
    for (int m = 32; m >= LPR; m >>= 1) {          // combine row groups
        acc.x += __shfl_xor(acc.x, m, 64);
        acc.y += __shfl_xor(acc.y, m, 64);
        acc.z += __shfl_xor(acc.z, m, 64);
        acc.w += __shfl_xor(acc.w, m, 64);
    }
    if (g == 0) {
        if constexpr (OUT_BIAS) {
            float4 bo = reinterpret_cast<const float4*>(bias)[c];
            acc.x += bo.x; acc.y += bo.y; acc.z += bo.z; acc.w += bo.w;
        }
        reinterpret_cast<float4*>(OUT)[(size_t)w * LPR + c] = acc;
    }
}

// ---------------- launch ----------------

extern "C" void kernel_launch(void* const* d_in, const int* in_sizes, int n_in,
                              void* d_out, int out_size, void* d_ws, size_t ws_size,
                              hipStream_t stream) {
    const float* x  = (const float*)d_in[0];
    const int*   ei = (const int*)  d_in[1];
    const float* W1 = (const float*)d_in[2];
    const float* b1 = (const float*)d_in[3];
    const float* W2 = (const float*)d_in[4];
    const float* b2 = (const float*)d_in[5];
    float* out = (float*)d_out;

    const int* row = ei;             // sources
    const int* col = ei + N_EDGES;   // targets

    // workspace layout
    char* ws = (char*)d_ws;
    int*   gcur   = (int*)ws;                                    // NBKT
    int*   gbase  = gcur + 128;                                  // NBKT+1
    int*   rowptr = gbase + 128;                                 // N+1
    float* dinv   = (float*)(rowptr + ((N_NODES + 256) & ~255)); // N
    int*   srows  = (int*)(dinv + ((N_NODES + 255) & ~255));     // E
    float* bufH   = (float*)(srows + ((N_EDGES + 255) & ~255));  // N*128
    float* bufAgg = bufH + (size_t)N_NODES * 128;                // N*128
    int*   pairs  = (int*)bufAgg;   // NBKT*CAP ints (7.2MB) — dead before gather1

    // 1) CSR by destination + dinv (bucketed, write-locality-aware)
    k_zero_small<<<1, 128, 0, stream>>>(gcur, NBKT);
    k_bucket    <<<NBLK_A, 256, 0, stream>>>(row, col, gcur, pairs);
    k_bases     <<<1, 128, 0, stream>>>(gcur, gbase, rowptr);
    k_fillB     <<<NBKT, 256, 0, stream>>>(gcur, gbase, pairs, rowptr, dinv, srows);

    // 2) h1 = x@W1
    k_gemm<128, 32, 2, false><<<(N_NODES + 127) / 128, 256, 0, stream>>>(
        x, W1, nullptr, bufH, N_NODES);

    // 3) agg1 = gather(h1) (self-loop fused)
    k_gather<128, false><<<(N_NODES + 3) / 4, 256, 0, stream>>>(
        rowptr, srows, dinv, bufH, nullptr, bufAgg, N_NODES);

    // 4) h2 = relu(agg1+b1)@W2
    k_gemm<64, 16, 2, true><<<(N_NODES + 127) / 128, 256, 0, stream>>>(
        bufAgg, W2, b1, bufH, N_NODES);

    // 5) out = gather(h2) + b2
    k_gather<64, true><<<(N_NODES + 3) / 4, 256, 0, stream>>>(
        rowptr, srows, dinv, bufH, b2, out, N_NODES);
}

// Round 5
// 234.044 us; speedup vs baseline: 18.1044x; 1.5926x over previous
//
#include <hip/hip_runtime.h>
#include <hip/hip_fp16.h>

#define N_NODES 100000
#define N_EDGES 1600000
#define K_DIM   128

#define CHUNK_LG 10
#define CHUNK    1024                                    // nodes per bucket
#define NBKT     ((N_NODES + CHUNK - 1) / CHUNK)         // 98
#define CAP      18432
#define EPB      4096                                    // edges per phase-A block
#define NBLK_A   ((N_EDGES + EPB - 1) / EPB)             // 391

typedef _Float16 half8 __attribute__((ext_vector_type(8)));
typedef float    f32x4 __attribute__((ext_vector_type(4)));

// ---------------- CSR build, bucketed (unchanged from R4) ----------------

__global__ __launch_bounds__(128) void k_zero_small(int* p, int n) {
    int i = threadIdx.x;
    if (i < n) p[i] = 0;
}

__global__ __launch_bounds__(256) void k_bucket(const int* __restrict__ row,
                                                const int* __restrict__ col,
                                                int* __restrict__ gcur,
                                                int* __restrict__ pairs) {
    __shared__ int hist[NBKT], sbase[NBKT], lcur[NBKT];
    int t = threadIdx.x;
    if (t < NBKT) { hist[t] = 0; lcur[t] = 0; }
    __syncthreads();
    int base = blockIdx.x * EPB;
    int myb[16], myp[16];
#pragma unroll
    for (int j = 0; j < 16; ++j) {
        int i = base + t + j * 256;
        int b = -1, p = 0;
        if (i < N_EDGES) {
            int r = row[i], c = col[i];
            b = c >> CHUNK_LG;
            p = ((c & (CHUNK - 1)) << 17) | r;
            atomicAdd(&hist[b], 1);
        }
        myb[j] = b; myp[j] = p;
    }
    __syncthreads();
    if (t < NBKT) {
        int c = hist[t];
        sbase[t] = c ? atomicAdd(&gcur[t], c) : 0;
    }
    __syncthreads();
#pragma unroll
    for (int j = 0; j < 16; ++j) {
        int b = myb[j];
        if (b >= 0) {
            int pos = sbase[b] + atomicAdd(&lcur[b], 1);
            pairs[b * CAP + pos] = myp[j];
        }
    }
}

__global__ __launch_bounds__(128) void k_bases(const int* __restrict__ gcur,
                                               int* __restrict__ gbase,
                                               int* __restrict__ rowptr) {
    __shared__ int sm[128];
    int t = threadIdx.x;
    int v = (t < NBKT) ? gcur[t] : 0;
    sm[t] = v;
    __syncthreads();
    for (int off = 1; off < 128; off <<= 1) {
        int u = (t >= off) ? sm[t - off] : 0;
        __syncthreads();
        sm[t] += u;
        __syncthreads();
    }
    if (t < NBKT) gbase[t] = sm[t] - v;
    if (t == 127) rowptr[N_NODES] = sm[127];
}

__global__ __launch_bounds__(256) void k_fillB(const int* __restrict__ gcur,
                                               const int* __restrict__ gbase,
                                               const int* __restrict__ pairs,
                                               int* __restrict__ rowptr,
                                               float* __restrict__ dinv,
                                               int* __restrict__ srows) {
    __shared__ int deg[CHUNK];
    __shared__ int curs[CHUNK];
    __shared__ int psum[256];
    int b = blockIdx.x, t = threadIdx.x;
    int nbase = b << CHUNK_LG;
    int nn = min(CHUNK, N_NODES - nbase);
    int cnt = gcur[b];
    int gb = gbase[b];
    const int* mp = pairs + b * CAP;

    for (int i = t; i < CHUNK; i += 256) deg[i] = 0;
    __syncthreads();
    for (int i = t; i < cnt; i += 256) atomicAdd(&deg[mp[i] >> 17], 1);
    __syncthreads();

    int i0 = t * 4;
    int d0 = deg[i0], d1 = deg[i0 + 1], d2 = deg[i0 + 2], d3 = deg[i0 + 3];
    int s4 = d0 + d1 + d2 + d3;
    psum[t] = s4;
    __syncthreads();
    for (int off = 1; off < 256; off <<= 1) {
        int u = (t >= off) ? psum[t - off] : 0;
        __syncthreads();
        psum[t] += u;
        __syncthreads();
    }
    int ex = gb + psum[t] - s4;
    int o0 = ex, o1 = o0 + d0, o2 = o1 + d1, o3 = o2 + d2;
    curs[i0] = o0; curs[i0 + 1] = o1; curs[i0 + 2] = o2; curs[i0 + 3] = o3;
    if (i0 + 3 < nn) {
        *reinterpret_cast<int4*>(rowptr + nbase + i0) = make_int4(o0, o1, o2, o3);
        float4 dv = make_float4(rsqrtf(1.f + (float)d0), rsqrtf(1.f + (float)d1),
                                rsqrtf(1.f + (float)d2), rsqrtf(1.f + (float)d3));
        *reinterpret_cast<float4*>(dinv + nbase + i0) = dv;
    } else {
        int oo[4] = {o0, o1, o2, o3};
        int dd[4] = {d0, d1, d2, d3};
        for (int j = 0; j < 4; ++j) if (i0 + j < nn) {
            rowptr[nbase + i0 + j] = oo[j];
            dinv[nbase + i0 + j] = rsqrtf(1.f + (float)dd[j]);
        }
    }
    __syncthreads();
    for (int i = t; i < cnt; i += 256) {
        int v = mp[i];
        int pos = atomicAdd(&curs[v >> 17], 1);
        srows[pos] = v & 0x1FFFF;
    }
}

// ---------------- f16 MFMA GEMM: H = A' @ W,  H stored f16 ----------------
// A' = A (fp32, layer 1)  or  relu(Ah(f16) + b_in) (layer 2).
// 256 thr = 4 waves; wave owns 16 rows; block = 64 rows. W^T staged in LDS
// (f16, +8 pad -> bank-uniform ds_read_b128). mfma_f32_16x16x32_f16:
//   A frag: row=lane&15, k=(lane>>4)*8+j (8 contiguous k)
//   C/D   : col=lane&15, row=(lane>>4)*4+reg
template<int NOUT, bool A_HALF_RELU>
__global__ __launch_bounds__(256) void k_gemm_mfma(
    const float* __restrict__ Af, const _Float16* __restrict__ Ah,
    const float* __restrict__ W, const float* __restrict__ b_in,
    _Float16* __restrict__ Hout, int nrows)
{
    constexpr int KD = K_DIM;
    constexpr int NT = NOUT / 16;            // 16-col tiles: 8 or 4
    __shared__ _Float16 Blds[NOUT][KD + 8];

    for (int i = threadIdx.x * 4; i < KD * NOUT; i += 256 * 4) {
        int k = i / NOUT, n = i % NOUT;      // W row-major [KD][NOUT]
        float4 wv = *reinterpret_cast<const float4*>(W + i);
        Blds[n + 0][k] = (_Float16)wv.x;
        Blds[n + 1][k] = (_Float16)wv.y;
        Blds[n + 2][k] = (_Float16)wv.z;
        Blds[n + 3][k] = (_Float16)wv.w;
    }
    __syncthreads();

    const int wave = threadIdx.x >> 6;
    const int lane = threadIdx.x & 63;
    const int r16  = lane & 15;
    const int kg   = lane >> 4;              // 0..3
    const int row  = blockIdx.x * 64 + wave * 16 + r16;
    const bool rowok = row < nrows;

    f32x4 acc[NT];
#pragma unroll
    for (int ct = 0; ct < NT; ++ct) acc[ct] = (f32x4){0.f, 0.f, 0.f, 0.f};

#pragma unroll
    for (int kc = 0; kc < KD / 32; ++kc) {
        const int k0 = kc * 32 + kg * 8;
        half8 a;
        if constexpr (A_HALF_RELU) {
            uint4 raw = make_uint4(0, 0, 0, 0);
            if (rowok)
                raw = *reinterpret_cast<const uint4*>(Ah + (size_t)row * KD + k0);
            const __half2* hp = reinterpret_cast<const __half2*>(&raw);
            float4 bA = *reinterpret_cast<const float4*>(b_in + k0);
            float4 bB = *reinterpret_cast<const float4*>(b_in + k0 + 4);
            float2 f0 = __half22float2(hp[0]);
            float2 f1 = __half22float2(hp[1]);
            float2 f2 = __half22float2(hp[2]);
            float2 f3 = __half22float2(hp[3]);
            a[0] = (_Float16)fmaxf(f0.x + bA.x, 0.f);
            a[1] = (_Float16)fmaxf(f0.y + bA.y, 0.f);
            a[2] = (_Float16)fmaxf(f1.x + bA.z, 0.f);
            a[3] = (_Float16)fmaxf(f1.y + bA.w, 0.f);
            a[4] = (_Float16)fmaxf(f2.x + bB.x, 0.f);
            a[5] = (_Float16)fmaxf(f2.y + bB.y, 0.f);
            a[6] = (_Float16)fmaxf(f3.x + bB.z, 0.f);
            a[7] = (_Float16)fmaxf(f3.y + bB.w, 0.f);
        } else {
            float4 xa = make_float4(0.f, 0.f, 0.f, 0.f), xb = xa;
            if (rowok) {
                const float4* ap = reinterpret_cast<const float4*>(
                    Af + (size_t)row * KD + k0);
                xa = ap[0]; xb = ap[1];
            }
            a[0] = (_Float16)xa.x; a[1] = (_Float16)xa.y;
            a[2] = (_Float16)xa.z; a[3] = (_Float16)xa.w;
            a[4] = (_Float16)xb.x; a[5] = (_Float16)xb.y;
            a[6] = (_Float16)xb.z; a[7] = (_Float16)xb.w;
        }
#pragma unroll
        for (int ct = 0; ct < NT; ++ct) {
            half8 b = *reinterpret_cast<const half8*>(&Blds[ct * 16 + r16][k0]);
            acc[ct] = __builtin_amdgcn_mfma_f32_16x16x32_f16(a, b, acc[ct], 0, 0, 0);
        }
    }

    const int orow0 = blockIdx.x * 64 + wave * 16 + kg * 4;
#pragma unroll
    for (int r = 0; r < 4; ++r) {
        int orow = orow0 + r;
        if (orow < nrows) {
#pragma unroll
            for (int ct = 0; ct < NT; ++ct)
                Hout[(size_t)orow * NOUT + ct * 16 + r16] = (_Float16)acc[ct][r];
        }
    }
}

// ---------------- gather (f16 source): one wave per destination ----------
__device__ __forceinline__ void fma8(uint4 v, float wgt, float (&acc)[8]) {
    const __half2* h = reinterpret_cast<const __half2*>(&v);
#pragma unroll
    for (int j = 0; j < 4; ++j) {
        float2 f = __half22float2(h[j]);
        acc[2 * j]     = fmaf(f.x, wgt, acc[2 * j]);
        acc[2 * j + 1] = fmaf(f.y, wgt, acc[2 * j + 1]);
    }
}

// OUT[i] = sum_e H[row_e]*dinv_r*dinv_i + H[i]*dinv_i^2 (+bias)
// F: feature width. OUT_HALF: write f16 (intermediate) vs fp32 (+bias, final)
template<int F, bool OUT_HALF>
__global__ __launch_bounds__(256) void k_gather_h(
    const int* __restrict__ rowptr, const int* __restrict__ srows,
    const float* __restrict__ dinv, const _Float16* __restrict__ H,
    const float* __restrict__ bias, void* __restrict__ OUT, int n)
{
    constexpr int LPR = F / 8;     // lanes per row (16 or 8), 8 f16 per lane
    constexpr int GR  = 64 / LPR;  // rows per wave-load (4 or 8)
    int w = blockIdx.x * 4 + (threadIdx.x >> 6);
    if (w >= n) return;
    int lane = threadIdx.x & 63;
    int g = lane / LPR;
    int c = lane % LPR;            // uint4 slot within row
    float di = dinv[w];
    int s = rowptr[w], e = rowptr[w + 1];
    const uint4* Hp = reinterpret_cast<const uint4*>(H);

    float acc[8];
#pragma unroll
    for (int j = 0; j < 8; ++j) acc[j] = 0.f;
    uint4 hv = Hp[(size_t)w * LPR + c];                 // self row
    fma8(hv, (g == 0) ? di * di : 0.f, acc);

    for (int k = s; k < e; k += 2 * GR) {
        int k0 = k + g, k1 = k + GR + g;
        int kk0 = min(k0, e - 1), kk1 = min(k1, e - 1);
        int r0 = srows[kk0], r1 = srows[kk1];
        float w0 = (k0 < e) ? dinv[r0] * di : 0.f;
        float w1 = (k1 < e) ? dinv[r1] * di : 0.f;
        uint4 h0 = Hp[(size_t)r0 * LPR + c];
        uint4 h1 = Hp[(size_t)r1 * LPR + c];
        fma8(h0, w0, acc);
        fma8(h1, w1, acc);
    }

#pragma unroll
    for (int m = 32; m >= LPR; m >>= 1) {
#pragma unroll
        for (int j = 0; j < 8; ++j)
            acc[j] += __shfl_xor(acc[j], m, 64);
    }

    if (g == 0) {
        if constexpr (OUT_HALF) {
            union { uint4 u; __half2 h[4]; } P;
#pragma unroll
            for (int j = 0; j < 4; ++j)
                P.h[j] = __floats2half2_rn(acc[2 * j], acc[2 * j + 1]);
            reinterpret_cast<uint4*>(OUT)[(size_t)w * LPR + c] = P.u;
        } else {
            const float4* bp = reinterpret_cast<const float4*>(bias + c * 8);
            float4 b0 = bp[0], b1 = bp[1];
            float4 o0 = make_float4(acc[0] + b0.x, acc[1] + b0.y,
                                    acc[2] + b0.z, acc[3] + b0.w);
            float4 o1 = make_float4(acc[4] + b1.x, acc[5] + b1.y,
                                    acc[6] + b1.z, acc[7] + b1.w);
            float* op = (float*)OUT + (size_t)w * F + c * 8;
            *reinterpret_cast<float4*>(op)     = o0;
            *reinterpret_cast<float4*>(op + 4) = o1;
        }
    }
}

// ---------------- launch ----------------

extern "C" void kernel_launch(void* const* d_in, const int* in_sizes, int n_in,
                              void* d_out, int out_size, void* d_ws, size_t ws_size,
                              hipStream_t stream) {
    const float* x  = (const float*)d_in[0];
    const int*   ei = (const int*)  d_in[1];
    const float* W1 = (const float*)d_in[2];
    const float* b1 = (const float*)d_in[3];
    const float* W2 = (const float*)d_in[4];
    const float* b2 = (const float*)d_in[5];
    float* out = (float*)d_out;

    const int* row = ei;             // sources
    const int* col = ei + N_EDGES;   // targets

    // workspace layout
    char* ws = (char*)d_ws;
    int*   gcur   = (int*)ws;                                      // NBKT
    int*   gbase  = gcur + 128;
    int*   rowptr = gbase + 128;                                   // N+1
    float* dinv   = (float*)(rowptr + ((N_NODES + 256) & ~255));   // N
    int*   srows  = (int*)(dinv + ((N_NODES + 255) & ~255));       // E
    _Float16* bufH   = (_Float16*)(srows + ((N_EDGES + 255) & ~255)); // N*128 f16
    _Float16* bufAgg = bufH + (size_t)N_NODES * 128;               // N*128 f16
    int*   pairs  = (int*)bufAgg;    // 7.2MB, dead before gather1

    // 1) CSR by destination + dinv
    k_zero_small<<<1, 128, 0, stream>>>(gcur, NBKT);
    k_bucket    <<<NBLK_A, 256, 0, stream>>>(row, col, gcur, pairs);
    k_bases     <<<1, 128, 0, stream>>>(gcur, gbase, rowptr);
    k_fillB     <<<NBKT, 256, 0, stream>>>(gcur, gbase, pairs, rowptr, dinv, srows);

    // 2) h1 = x@W1 (f16 out)
    k_gemm_mfma<128, false><<<(N_NODES + 63) / 64, 256, 0, stream>>>(
        x, nullptr, W1, nullptr, bufH, N_NODES);

    // 3) agg1 = gather(h1), f16 out
    k_gather_h<128, true><<<(N_NODES + 3) / 4, 256, 0, stream>>>(
        rowptr, srows, dinv, bufH, nullptr, bufAgg, N_NODES);

    // 4) h2 = relu(agg1+b1)@W2 (f16 out)
    k_gemm_mfma<64, true><<<(N_NODES + 63) / 64, 256, 0, stream>>>(
        nullptr, bufAgg, W2, b1, bufH, N_NODES);

    // 5) out = gather(h2) + b2 (fp32 out)
    k_gather_h<64, false><<<(N_NODES + 3) / 4, 256, 0, stream>>>(
        rowptr, srows, dinv, bufH, b2, out, N_NODES);
}